// Round 1
// 911.561 us; speedup vs baseline: 1.0047x; 1.0047x over previous
//
#include <hip/hip_runtime.h>
#include <cstdint>
#include <cstddef>

#define EPS_F 1e-6f

// ---------- bf16 helpers ----------
__device__ inline unsigned short f2bf(float f) {
    union { float f; unsigned u; } v; v.f = f;
    unsigned r = v.u + 0x7fffu + ((v.u >> 16) & 1u);   // RNE
    return (unsigned short)(r >> 16);
}
__device__ inline float bf2f(unsigned u16) {           // low 16 bits used
    union { unsigned u; float f; } v; v.u = u16 << 16; return v.f;
}

typedef __attribute__((ext_vector_type(8))) __bf16 bf16x8;
typedef __attribute__((ext_vector_type(8))) short short8;
typedef __attribute__((ext_vector_type(8))) unsigned short ushort8;
typedef __attribute__((ext_vector_type(4))) float floatx4;
typedef __attribute__((ext_vector_type(4))) unsigned uintx4;

__device__ inline void async_load16(const void* g, void* l) {
    __builtin_amdgcn_global_load_lds((const __attribute__((address_space(1))) void*)g,
                                     (__attribute__((address_space(3))) void*)l,
                                     16, 0, 0);
}

#define LDS_OFF(p) ((unsigned)(unsigned long long)(const __attribute__((address_space(3))) void*)(p))

// ---------- cast fp32 -> bf16, 8 elems/thread (16B store) ----------
__global__ void cast_x_kernel(const float* __restrict__ in, unsigned short* __restrict__ out, int n8) {
    int i = blockIdx.x * blockDim.x + threadIdx.x;
    if (i < n8) {
        float4 a = ((const float4*)in)[2 * i];
        float4 b = ((const float4*)in)[2 * i + 1];
        short8 o;
        o[0] = (short)f2bf(a.x); o[1] = (short)f2bf(a.y);
        o[2] = (short)f2bf(a.z); o[3] = (short)f2bf(a.w);
        o[4] = (short)f2bf(b.x); o[5] = (short)f2bf(b.y);
        o[6] = (short)f2bf(b.z); o[7] = (short)f2bf(b.w);
        ((short8*)out)[i] = o;
    }
}

// ---------- transpose + cast 4 weights in one dispatch (blockIdx.z selects) ----------
__global__ void transpose_cast_kernel(const float* __restrict__ W0, const float* __restrict__ W1,
                                      const float* __restrict__ W2, const float* __restrict__ W3,
                                      unsigned short* __restrict__ WtBase, int n) {
    const float* W = (blockIdx.z == 0) ? W0 : (blockIdx.z == 1) ? W1 : (blockIdx.z == 2) ? W2 : W3;
    unsigned short* Wt = WtBase + (size_t)blockIdx.z * n * n;
    __shared__ float tile[32][33];
    int bx = blockIdx.x * 32;
    int by = blockIdx.y * 32;
    int tx = threadIdx.x;        // 0..31
    int ty = threadIdx.y;        // 0..7
    #pragma unroll
    for (int i = 0; i < 32; i += 8)
        tile[ty + i][tx] = W[(size_t)(by + ty + i) * n + bx + tx];
    __syncthreads();
    #pragma unroll
    for (int i = 0; i < 32; i += 8)
        Wt[(size_t)(bx + ty + i) * n + by + tx] = f2bf(tile[tx][ty + i]);
}

// ---------- bf16 MFMA GEMM, 256x256 tile, BK=32, ring-4 LDS, counted vmcnt ----------
// Structure (T3/T4-style): raw s_barrier, never-drain vmcnt in steady state.
// Per iteration t (slot = t&3):
//   vmcnt(8)           -- tiles t+1,t+2 (4 loads each) stay in flight; tile t landed
//   s_barrier          -- all waves' tile-t loads landed (per-wave vmcnt + barrier)
//   stage(t+3)         -- writes slot (t-1)&3; its readers (iter t-1) all drained
//                         their ds_reads (lgkmcnt(0) precedes MFMA precedes this barrier)
//   12x asm ds_read_b128 ; lgkmcnt(0) ; sched_barrier ; 32x MFMA
// FINAL=0: fused QKV epilogue (elu+1 / mask), bf16 out. FINAL=1: +bias, fp32 out.
#define BMT 256
#define BNT 256
#define BKT 32
#define SLOT_ELEMS (BMT * BKT)   // 8192 bf16 = 16 KB per slot per matrix
#define DMODEL 2048

template<int FINAL>
__global__ __launch_bounds__(512, 2)
void gemm_kernel(const unsigned short* __restrict__ A,
                 const unsigned short* __restrict__ Bt,
                 const float* __restrict__ b0, const float* __restrict__ b1,
                 const float* __restrict__ b2,
                 const float* __restrict__ mask,
                 unsigned short* __restrict__ qo, unsigned short* __restrict__ ko,
                 unsigned short* __restrict__ vo,
                 float* __restrict__ Cf,
                 int M, int K) {
    // 4-deep ring, 16KB A + 16KB B per slot -> 128 KB LDS, 1 block/CU, 8 waves.
    // LDS chunk layout: slot row r, chunk c (16B) holds global chunk c ^ ((r>>1)&3).
    // ds_read bank check: quad-bank = (r&1)*4 + (quad ^ ((r>>1)&3)) -> 64 lanes spread
    // exactly 8 per 16B bank-quad (uniform, conflict-free).
    __shared__ __align__(16) unsigned short As[4 * SLOT_ELEMS];
    __shared__ __align__(16) unsigned short Bs[4 * SLOT_ELEMS];

    const int tid  = threadIdx.x;
    const int lane = tid & 63;
    const int wave = tid >> 6;     // 0..7
    const int wr   = wave >> 2;    // 0..1  (128-row M half)
    const int wc   = wave & 3;     // 0..3  (64-col N quarter)
    const int quad  = lane >> 4;
    const int row16 = lane & 15;

    // T1: XCD-aware swizzle (nwg % 8 == 0 in both uses). Consecutive swz share the
    // same B panel; each XCD gets nwg/8 consecutive swz = whole B columns (<=3MB in L2).
    const int nwg = (int)(gridDim.x * gridDim.y);
    const int bid = (int)(blockIdx.y * gridDim.x + blockIdx.x);
    const int cpx = nwg >> 3;
    const int swz = (bid & 7) * cpx + (bid >> 3);
    const int bm  = swz % (int)gridDim.x;
    const int bn  = swz / (int)gridDim.x;

    const int m0    = bm * BMT;
    const int nglob = bn * BNT;
    int mat = 0, n0 = nglob;
    const float* bias = b0;
    unsigned short* Cb = nullptr;
    if (!FINAL) {
        mat  = nglob >> 11;            // /DMODEL (BNT=256 divides DMODEL: no straddle)
        n0   = nglob & (DMODEL - 1);
        bias = (mat == 0) ? b0 : (mat == 1) ? b1 : b2;
        Cb   = (mat == 0) ? qo : (mat == 1) ? ko : vo;
    }

    floatx4 acc[8][4] = {};

    // staging: 1024 chunks per matrix per tile; 512 threads x 2 batches; 4 loads/thread/tile
    const unsigned short* gA[2];
    const unsigned short* gB[2];
    #pragma unroll
    for (int b = 0; b < 2; b++) {
        int s = b * 512 + tid;
        int r = s >> 2, c = s & 3;
        int cg = c ^ ((r >> 1) & 3);
        gA[b] = A  + (size_t)(m0 + r) * K + cg * 8;
        gB[b] = Bt + (size_t)(nglob + r) * K + cg * 8;
    }

    const unsigned asB = LDS_OFF(As);
    const unsigned bsB = LDS_OFF(Bs);
    // reader swizzle: want global chunk=quad of row r; r base is mult of 16 so
    // (r>>1)&3 == (row16>>1)&3  -> lane-constant, frag stride is a clean +1024B per i.
    const unsigned cP    = (unsigned)(quad ^ ((row16 >> 1) & 3));
    const unsigned aLane = asB + (unsigned)(wr * 8192 + row16 * 64) + cP * 16u;
    const unsigned bLane = bsB + (unsigned)(wc * 4096 + row16 * 64) + cP * 16u;

    auto stage = [&](int tt, int sl) {
        const int koff = tt * BKT;
        #pragma unroll
        for (int b = 0; b < 2; b++) {
            int s = b * 512 + tid;
            async_load16(gA[b] + koff, As + sl * SLOT_ELEMS + s * 8);
            async_load16(gB[b] + koff, Bs + sl * SLOT_ELEMS + s * 8);
        }
    };

    const int NT = K / BKT;     // 64
    stage(0, 0); stage(1, 1); stage(2, 2);

    for (int t = 0; t < NT; ++t) {
        const int slot = t & 3;
        // counted wait: tiles t+1,t+2 (8 loads) stay outstanding; tail peels exactly.
        if (t < NT - 2)       asm volatile("s_waitcnt vmcnt(8)" ::: "memory");
        else if (t == NT - 2) asm volatile("s_waitcnt vmcnt(4)" ::: "memory");
        else                  asm volatile("s_waitcnt vmcnt(0)" ::: "memory");
        __builtin_amdgcn_s_barrier();
        asm volatile("" ::: "memory");         // keep stage below the barrier
        if (t + 3 < NT) stage(t + 3, (t + 3) & 3);

        const unsigned aOff = aLane + (unsigned)slot * (SLOT_ELEMS * 2);
        const unsigned bOff = bLane + (unsigned)slot * (SLOT_ELEMS * 2);
        uintx4 araw[8], braw[4];
        #pragma unroll
        for (int i = 0; i < 8; i++)
            asm volatile("ds_read_b128 %0, %1" : "=v"(araw[i]) : "v"(aOff + (unsigned)(i * 1024)));
        #pragma unroll
        for (int j = 0; j < 4; j++)
            asm volatile("ds_read_b128 %0, %1" : "=v"(braw[j]) : "v"(bOff + (unsigned)(j * 1024)));
        asm volatile("s_waitcnt lgkmcnt(0)");
        __builtin_amdgcn_sched_barrier(0);     // rule 18: MFMA must not hoist above the wait
        __builtin_amdgcn_s_setprio(1);
        #pragma unroll
        for (int i = 0; i < 8; i++) {
            bf16x8 af = __builtin_bit_cast(bf16x8, araw[i]);
            #pragma unroll
            for (int j = 0; j < 4; j++)
                acc[i][j] = __builtin_amdgcn_mfma_f32_16x16x32_bf16(
                    af, __builtin_bit_cast(bf16x8, braw[j]), acc[i][j], 0, 0, 0);
        }
        __builtin_amdgcn_s_setprio(0);
    }

    // epilogue: D row = wr*128 + i*16 + quad*4 + r, col = wc*64 + j*16 + row16
    float bcache[4];
    #pragma unroll
    for (int j = 0; j < 4; j++) bcache[j] = bias[n0 + wc * 64 + j * 16 + row16];
    #pragma unroll
    for (int i = 0; i < 8; i++) {
        #pragma unroll
        for (int r = 0; r < 4; r++) {
            int row = m0 + wr * 128 + i * 16 + quad * 4 + r;
            float mr = 1.0f;
            if (!FINAL && mat >= 1) mr = mask[row];
            #pragma unroll
            for (int j = 0; j < 4; j++) {
                int col = n0 + wc * 64 + j * 16 + row16;
                float v = acc[i][j][r] + bcache[j];
                if (FINAL) {
                    Cf[(size_t)row * DMODEL + col] = v;
                } else {
                    if (mat <= 1) v = (v > 0.f) ? (v + 1.f) : __expf(v);  // elu+1
                    v *= mr;
                    Cb[(size_t)row * DMODEL + col] = f2bf(v);
                }
            }
        }
    }
}

// ---------- linear-attention scan (elementwise kv), chunked 3-pass ----------
#define SL    4096
#define SD    2048
#define SH    16
#define CHUNK 64
#define NCH   64   // SL / CHUNK

// Pass A: per-(b,h,chunk) partial sums. lane = tg*16+dg: 4 t-rows in flight,
// 16B/lane loads; summation is order-free so cross-lane combine at the end.
__global__ void scan_partial_kernel(const unsigned short* __restrict__ k,
                                    const unsigned short* __restrict__ v,
                                    float* __restrict__ sumK, float* __restrict__ sumKV) {
    int blk = blockIdx.x;
    int c = blk & (NCH - 1), bh = blk >> 6;
    int b = bh >> 4, h = bh & (SH - 1);
    int lane = threadIdx.x;
    int tg = lane >> 4, dg = lane & 15;
    size_t base = ((size_t)(b * SL + c * CHUNK + tg)) * SD + h * 128 + dg * 8;
    float sk[8] = {0.f, 0.f, 0.f, 0.f, 0.f, 0.f, 0.f, 0.f};
    float skv[8] = {0.f, 0.f, 0.f, 0.f, 0.f, 0.f, 0.f, 0.f};
    for (int it = 0; it < CHUNK / 4; it++) {
        ushort8 kw = *(const ushort8*)(k + base);
        ushort8 vw = *(const ushort8*)(v + base);
        #pragma unroll
        for (int j = 0; j < 8; j++) {
            float kf = bf2f(kw[j]);
            float vf = bf2f(vw[j]);
            sk[j] += kf; skv[j] += kf * vf;
        }
        base += (size_t)4 * SD;
    }
    #pragma unroll
    for (int j = 0; j < 8; j++) {
        sk[j]  += __shfl_xor(sk[j], 16);  sk[j]  += __shfl_xor(sk[j], 32);
        skv[j] += __shfl_xor(skv[j], 16); skv[j] += __shfl_xor(skv[j], 32);
    }
    if (tg == 0) {
        size_t o = ((size_t)bh * NCH + c) * 128 + dg * 8;
        *(float4*)(sumK  + o)     = make_float4(sk[0], sk[1], sk[2], sk[3]);
        *(float4*)(sumK  + o + 4) = make_float4(sk[4], sk[5], sk[6], sk[7]);
        *(float4*)(sumKV + o)     = make_float4(skv[0], skv[1], skv[2], skv[3]);
        *(float4*)(sumKV + o + 4) = make_float4(skv[4], skv[5], skv[6], skv[7]);
    }
}

// Pass B: exclusive scan of chunk sums along chunk axis, per (b,h,d)
__global__ void scan_offsets_kernel(const float* __restrict__ sumK, const float* __restrict__ sumKV,
                                    float* __restrict__ offK, float* __restrict__ offKV) {
    int bh = blockIdx.x;
    int d  = threadIdx.x;   // 0..127
    float aK = 0.f, aKV = 0.f;
    for (int c = 0; c < NCH; c++) {
        size_t o = ((size_t)bh * NCH + c) * 128 + d;
        float sk = sumK[o], skv = sumKV[o];
        offK[o] = aK; offKV[o] = aKV;
        aK += sk; aKV += skv;
    }
}

// Pass C: within-chunk sequential scan, 4-timestep batches: 12 loads in flight,
// 4 interleaved shuffle-reduction trees amortize the 6-step latency.
__global__ void scan_final_kernel(const unsigned short* __restrict__ q,
                                  const unsigned short* __restrict__ k,
                                  const unsigned short* __restrict__ v,
                                  const float* __restrict__ offK, const float* __restrict__ offKV,
                                  const float* __restrict__ mask,
                                  unsigned short* __restrict__ out) {
    int blk = blockIdx.x;
    int c = blk & (NCH - 1), bh = blk >> 6;
    int b = bh >> 4, h = bh & (SH - 1);
    int lane = threadIdx.x;
    size_t ob = ((size_t)bh * NCH + c) * 128 + 2 * lane;
    float2 kcv = *(const float2*)(offK  + ob);
    float2 kvv = *(const float2*)(offKV + ob);
    float kc0 = kcv.x, kc1 = kcv.y, kv0 = kvv.x, kv1 = kvv.y;
    size_t base = ((size_t)(b * SL + c * CHUNK)) * SD + h * 128 + 2 * lane;
    const float* mrow = mask + (size_t)b * SL + c * CHUNK;
    for (int s = 0; s < CHUNK / 4; s++) {
        unsigned kw[4], vw[4], qw[4];
        #pragma unroll
        for (int u = 0; u < 4; u++) {
            size_t a = base + (size_t)u * SD;
            kw[u] = *(const unsigned*)(k + a);
            vw[u] = *(const unsigned*)(v + a);
            qw[u] = *(const unsigned*)(q + a);
        }
        float p[4], n0[4], n1[4];
        #pragma unroll
        for (int u = 0; u < 4; u++) {
            float kk0 = bf2f(kw[u] & 0xffff), kk1 = bf2f(kw[u] >> 16);
            float vv0 = bf2f(vw[u] & 0xffff), vv1 = bf2f(vw[u] >> 16);
            float qq0 = bf2f(qw[u] & 0xffff), qq1 = bf2f(qw[u] >> 16);
            kc0 += kk0; kc1 += kk1;
            kv0 += kk0 * vv0; kv1 += kk1 * vv1;
            p[u]  = qq0 * kc0 + qq1 * kc1;
            n0[u] = qq0 * kv0; n1[u] = qq1 * kv1;
        }
        #pragma unroll
        for (int off = 32; off > 0; off >>= 1) {
            #pragma unroll
            for (int u = 0; u < 4; u++) p[u] += __shfl_xor(p[u], off);
        }
        #pragma unroll
        for (int u = 0; u < 4; u++) {
            float z = (p[u] + EPS_F) * mrow[s * 4 + u];
            float inv = 1.0f / z;
            unsigned o0 = f2bf(n0[u] * inv);
            unsigned o1 = f2bf(n1[u] * inv);
            *(unsigned*)(out + base + (size_t)u * SD) = o0 | (o1 << 16);
        }
        base += (size_t)4 * SD;
    }
}

// ---------- launcher ----------
extern "C" void kernel_launch(void* const* d_in, const int* in_sizes, int n_in,
                              void* d_out, int out_size, void* d_ws, size_t ws_size,
                              hipStream_t stream) {
    const float* x  = (const float*)d_in[0];
    const float* am = (const float*)d_in[1];
    const float* Wq = (const float*)d_in[2];
    const float* bq = (const float*)d_in[3];
    const float* Wk = (const float*)d_in[4];
    const float* bk = (const float*)d_in[5];
    const float* Wv = (const float*)d_in[6];
    const float* bv = (const float*)d_in[7];
    const float* Wo = (const float*)d_in[8];
    const float* bo = (const float*)d_in[9];
    float* out = (float*)d_out;

    const int Bb = 4, L = 4096, D = 2048;
    const int M = Bb * L;                       // 16384
    const size_t MD = (size_t)M * D;            // 33,554,432

    // workspace carve-up (~310 MB). attn aliases xb (xb dead after QKV GEMM).
    char* w = (char*)d_ws;
    unsigned short* xb    = (unsigned short*)w; w += MD * 2;
    unsigned short* qb    = (unsigned short*)w; w += MD * 2;
    unsigned short* kb    = (unsigned short*)w; w += MD * 2;
    unsigned short* vb    = (unsigned short*)w; w += MD * 2;
    unsigned short* WT    = (unsigned short*)w; w += (size_t)4 * D * D * 2; // [WqT;WkT;WvT;WoT]
    float* sumK  = (float*)w; w += (size_t)64 * NCH * 128 * 4;
    float* sumKV = (float*)w; w += (size_t)64 * NCH * 128 * 4;
    float* offK  = (float*)w; w += (size_t)64 * NCH * 128 * 4;
    float* offKV = (float*)w; w += (size_t)64 * NCH * 128 * 4;
    unsigned short* attnb = xb;                 // alias

    // 1) casts / transposes
    int n8 = (int)(MD / 8);
    cast_x_kernel<<<(n8 + 255) / 256, 256, 0, stream>>>(x, xb, n8);
    dim3 tb(32, 8);
    dim3 tg(D / 32, D / 32, 4);
    transpose_cast_kernel<<<tg, tb, 0, stream>>>(Wq, Wk, Wv, Wo, WT, D);

    // 2) fused QKV projection (N = 3*D), epilogues fused. grid 64x24 = 1536 (%8==0)
    dim3 gq(M / BMT, 3 * D / BNT);
    gemm_kernel<0><<<gq, 512, 0, stream>>>(xb, WT, bq, bk, bv, am, qb, kb, vb, nullptr, M, D);

    // 3) chunked linear-attention scan
    scan_partial_kernel<<<64 * NCH, 64, 0, stream>>>(kb, vb, sumK, sumKV);
    scan_offsets_kernel<<<64, 128, 0, stream>>>(sumK, sumKV, offK, offKV);
    scan_final_kernel<<<64 * NCH, 64, 0, stream>>>(qb, kb, vb, offK, offKV, am, attnb);

    // 4) output projection -> fp32 d_out. grid 64x8 = 512 (%8==0)
    dim3 go(M / BMT, D / BNT);
    gemm_kernel<1><<<go, 512, 0, stream>>>(attnb, WT + (size_t)3 * D * D, bo, nullptr, nullptr,
                                           nullptr, nullptr, nullptr, nullptr, out, M, D);
}

// Round 2
// 889.150 us; speedup vs baseline: 1.0300x; 1.0252x over previous
//
#include <hip/hip_runtime.h>
#include <cstdint>
#include <cstddef>

#define EPS_F 1e-6f

// ---------- bf16 helpers ----------
__device__ inline unsigned short f2bf(float f) {
    union { float f; unsigned u; } v; v.f = f;
    unsigned r = v.u + 0x7fffu + ((v.u >> 16) & 1u);   // RNE
    return (unsigned short)(r >> 16);
}
__device__ inline float bf2f(unsigned u16) {           // low 16 bits used
    union { unsigned u; float f; } v; v.u = u16 << 16; return v.f;
}

typedef __attribute__((ext_vector_type(8))) __bf16 bf16x8;
typedef __attribute__((ext_vector_type(8))) short short8;
typedef __attribute__((ext_vector_type(8))) unsigned short ushort8;
typedef __attribute__((ext_vector_type(4))) float floatx4;
typedef __attribute__((ext_vector_type(4))) unsigned uintx4;

__device__ inline void async_load16(const void* g, void* l) {
    __builtin_amdgcn_global_load_lds((const __attribute__((address_space(1))) void*)g,
                                     (__attribute__((address_space(3))) void*)l,
                                     16, 0, 0);
}

#define LDS_OFF(p) ((unsigned)(unsigned long long)(const __attribute__((address_space(3))) void*)(p))

// ---------- cast fp32 -> bf16, 8 elems/thread (16B store) ----------
__global__ void cast_x_kernel(const float* __restrict__ in, unsigned short* __restrict__ out, int n8) {
    int i = blockIdx.x * blockDim.x + threadIdx.x;
    if (i < n8) {
        float4 a = ((const float4*)in)[2 * i];
        float4 b = ((const float4*)in)[2 * i + 1];
        short8 o;
        o[0] = (short)f2bf(a.x); o[1] = (short)f2bf(a.y);
        o[2] = (short)f2bf(a.z); o[3] = (short)f2bf(a.w);
        o[4] = (short)f2bf(b.x); o[5] = (short)f2bf(b.y);
        o[6] = (short)f2bf(b.z); o[7] = (short)f2bf(b.w);
        ((short8*)out)[i] = o;
    }
}

// ---------- transpose + cast 4 weights in one dispatch (blockIdx.z selects) ----------
__global__ void transpose_cast_kernel(const float* __restrict__ W0, const float* __restrict__ W1,
                                      const float* __restrict__ W2, const float* __restrict__ W3,
                                      unsigned short* __restrict__ WtBase, int n) {
    const float* W = (blockIdx.z == 0) ? W0 : (blockIdx.z == 1) ? W1 : (blockIdx.z == 2) ? W2 : W3;
    unsigned short* Wt = WtBase + (size_t)blockIdx.z * n * n;
    __shared__ float tile[32][33];
    int bx = blockIdx.x * 32;
    int by = blockIdx.y * 32;
    int tx = threadIdx.x;        // 0..31
    int ty = threadIdx.y;        // 0..7
    #pragma unroll
    for (int i = 0; i < 32; i += 8)
        tile[ty + i][tx] = W[(size_t)(by + ty + i) * n + bx + tx];
    __syncthreads();
    #pragma unroll
    for (int i = 0; i < 32; i += 8)
        Wt[(size_t)(bx + ty + i) * n + by + tx] = f2bf(tile[tx][ty + i]);
}

// ---------- bf16 MFMA GEMM, 256x256 tile, BK=32, ring-4 LDS, pipelined reads ----------
// Per iteration t (slot = t&3), steady state:
//   vmcnt(4)            -- tile t+1 landed (t+2 stays in flight)
//   s_barrier           -- ALL waves' t+1 loads landed; slot (t-1) readers all done
//   stage(t+3)          -- into slot (t-1)&3
//   lgkmcnt(4)          -- af0(t)+bf(t) frags ready (af1(t) still in flight)
//   16 MFMA (i=0..3)    -- then issue af0(t+1)+bf(t+1) reads from slot (t+1)&3
//   lgkmcnt(8)          -- af1(t) ready (the 8 new reads stay in flight)
//   16 MFMA (i=4..7)    -- then issue af1(t+1) reads
// Reads for tile t+1 are legal at iter t: vmcnt(4)+barrier proved all waves' loads
// landed; slot (t+1)&3 != staged slot (t-1)&3 (differ by 2 mod 4); restage of
// (t+1)&3 is stage(t+5) at iter t+2, after a barrier that follows read completion.
#define BMT 256
#define BNT 256
#define BKT 32
#define SLOT_ELEMS (BMT * BKT)   // 8192 bf16 = 16 KB per slot per matrix
#define SLOT_BYTES 16384
#define DMODEL 2048

#define DSR(dst, base, OFF) \
    asm volatile("ds_read_b128 %0, %1 offset:" OFF : "=v"(dst) : "v"(base) : "memory")
#define READ_A0(f, base) { DSR(f[0], base, "0");    DSR(f[1], base, "1024"); \
                           DSR(f[2], base, "2048"); DSR(f[3], base, "3072"); }
#define READ_A1(f, base) { DSR(f[0], base, "4096"); DSR(f[1], base, "5120"); \
                           DSR(f[2], base, "6144"); DSR(f[3], base, "7168"); }
#define READ_B(f, base)  { DSR(f[0], base, "0");    DSR(f[1], base, "1024"); \
                           DSR(f[2], base, "2048"); DSR(f[3], base, "3072"); }

#define MFMA_HALF(i0, af, bf)                                                   \
    _Pragma("unroll")                                                           \
    for (int i_ = 0; i_ < 4; i_++) {                                            \
        bf16x8 a_ = __builtin_bit_cast(bf16x8, af[i_]);                         \
        _Pragma("unroll")                                                       \
        for (int j_ = 0; j_ < 4; j_++)                                          \
            acc[i0 + i_][j_] = __builtin_amdgcn_mfma_f32_16x16x32_bf16(         \
                a_, __builtin_bit_cast(bf16x8, bf[j_]), acc[i0 + i_][j_], 0, 0, 0); \
    }

#define GEMM_ITER(T, BCUR, BNXT)                                                \
  {                                                                             \
    const int T_ = (T);                                                         \
    if (T_ <= NT - 3)      asm volatile("s_waitcnt vmcnt(4)" ::: "memory");     \
    else if (T_ == NT - 2) asm volatile("s_waitcnt vmcnt(0)" ::: "memory");     \
    __builtin_amdgcn_s_barrier();                                               \
    __builtin_amdgcn_sched_barrier(0);                                          \
    if (T_ + 3 < NT) stage(T_ + 3, (T_ + 3) & 3);                               \
    asm volatile("s_waitcnt lgkmcnt(4)" ::: "memory");                          \
    __builtin_amdgcn_sched_barrier(0);                                          \
    __builtin_amdgcn_s_setprio(1);                                              \
    MFMA_HALF(0, af0, BCUR);                                                    \
    __builtin_amdgcn_s_setprio(0);                                              \
    const int tn_ = T_ + 1;                                                     \
    const unsigned aN_ = aLane + (unsigned)((tn_ & 3) * SLOT_BYTES);            \
    const unsigned bN_ = bLane + (unsigned)((tn_ & 3) * SLOT_BYTES);            \
    if (tn_ < NT) {                                                             \
      READ_A0(af0, aN_);                                                        \
      READ_B(BNXT, bN_);                                                        \
      asm volatile("s_waitcnt lgkmcnt(8)" ::: "memory");                        \
    } else {                                                                    \
      asm volatile("s_waitcnt lgkmcnt(0)" ::: "memory");                        \
    }                                                                           \
    __builtin_amdgcn_sched_barrier(0);                                          \
    __builtin_amdgcn_s_setprio(1);                                              \
    MFMA_HALF(4, af1, BCUR);                                                    \
    __builtin_amdgcn_s_setprio(0);                                              \
    if (tn_ < NT) { READ_A1(af1, aN_); }                                        \
  }

template<int FINAL>
__global__ __launch_bounds__(512, 2)
void gemm_kernel(const unsigned short* __restrict__ A,
                 const unsigned short* __restrict__ Bt,
                 const float* __restrict__ b0, const float* __restrict__ b1,
                 const float* __restrict__ b2,
                 const float* __restrict__ mask,
                 unsigned short* __restrict__ qo, unsigned short* __restrict__ ko,
                 unsigned short* __restrict__ vo,
                 float* __restrict__ Cf,
                 int M, int K) {
    // 4-deep ring, 16KB A + 16KB B per slot -> 128 KB LDS, 1 block/CU, 8 waves.
    // LDS chunk layout: slot row r, chunk c (16B) holds global chunk c ^ ((r>>1)&3)
    // -> reader quad-banks spread uniformly, 0 conflicts (verified by counters).
    __shared__ __align__(16) unsigned short As[4 * SLOT_ELEMS];
    __shared__ __align__(16) unsigned short Bs[4 * SLOT_ELEMS];

    const int tid  = threadIdx.x;
    const int lane = tid & 63;
    const int wave = tid >> 6;     // 0..7
    const int wr   = wave >> 2;    // 0..1  (128-row M half)
    const int wc   = wave & 3;     // 0..3  (64-col N quarter)
    const int quad  = lane >> 4;
    const int row16 = lane & 15;

    // T1: XCD-aware swizzle (nwg % 8 == 0 in both uses).
    const int nwg = (int)(gridDim.x * gridDim.y);
    const int bid = (int)(blockIdx.y * gridDim.x + blockIdx.x);
    const int cpx = nwg >> 3;
    const int swz = (bid & 7) * cpx + (bid >> 3);
    const int bm  = swz % (int)gridDim.x;
    const int bn  = swz / (int)gridDim.x;

    const int m0    = bm * BMT;
    const int nglob = bn * BNT;
    int mat = 0, n0 = nglob;
    const float* bias = b0;
    unsigned short* Cb = nullptr;
    if (!FINAL) {
        mat  = nglob >> 11;            // /DMODEL (BNT=256 divides DMODEL: no straddle)
        n0   = nglob & (DMODEL - 1);
        bias = (mat == 0) ? b0 : (mat == 1) ? b1 : b2;
        Cb   = (mat == 0) ? qo : (mat == 1) ? ko : vo;
    }

    floatx4 acc[8][4] = {};

    // staging: 1024 chunks per matrix per tile; 512 threads x 2 batches
    const unsigned short* gA[2];
    const unsigned short* gB[2];
    #pragma unroll
    for (int b = 0; b < 2; b++) {
        int s = b * 512 + tid;
        int r = s >> 2, c = s & 3;
        int cg = c ^ ((r >> 1) & 3);
        gA[b] = A  + (size_t)(m0 + r) * K + cg * 8;
        gB[b] = Bt + (size_t)(nglob + r) * K + cg * 8;
    }

    const unsigned asB = LDS_OFF(As);
    const unsigned bsB = LDS_OFF(Bs);
    // reader swizzle: (r>>1)&3 == (row16>>1)&3 for r = base16 + row16 -> lane-constant
    const unsigned cP    = (unsigned)(quad ^ ((row16 >> 1) & 3));
    const unsigned aLane = asB + (unsigned)(wr * 8192 + row16 * 64) + cP * 16u;
    const unsigned bLane = bsB + (unsigned)(wc * 4096 + row16 * 64) + cP * 16u;

    auto stage = [&](int tt, int sl) {
        const int koff = tt * BKT;
        #pragma unroll
        for (int b = 0; b < 2; b++) {
            int s = b * 512 + tid;
            async_load16(gA[b] + koff, As + sl * SLOT_ELEMS + s * 8);
            async_load16(gB[b] + koff, Bs + sl * SLOT_ELEMS + s * 8);
        }
    };

    const int NT = K / BKT;     // 64
    stage(0, 0); stage(1, 1); stage(2, 2);
    asm volatile("s_waitcnt vmcnt(8)" ::: "memory");   // tile 0 landed (mine)
    __builtin_amdgcn_s_barrier();                      // all waves' tile 0 landed
    __builtin_amdgcn_sched_barrier(0);

    uintx4 af0[4], af1[4], bfE[4], bfO[4];
    // prologue reads: tile 0 from slot 0 (issue order: af0+bfE first, af1 last)
    READ_A0(af0, aLane);
    READ_B(bfE, bLane);
    READ_A1(af1, aLane);

    for (int t = 0; t < NT; t += 2) {
        GEMM_ITER(t,     bfE, bfO);
        GEMM_ITER(t + 1, bfO, bfE);
    }

    // epilogue: D row = wr*128 + i*16 + quad*4 + r, col = wc*64 + j*16 + row16
    float bcache[4];
    #pragma unroll
    for (int j = 0; j < 4; j++) bcache[j] = bias[n0 + wc * 64 + j * 16 + row16];
    #pragma unroll
    for (int i = 0; i < 8; i++) {
        #pragma unroll
        for (int r = 0; r < 4; r++) {
            int row = m0 + wr * 128 + i * 16 + quad * 4 + r;
            float mr = 1.0f;
            if (!FINAL && mat >= 1) mr = mask[row];
            #pragma unroll
            for (int j = 0; j < 4; j++) {
                int col = n0 + wc * 64 + j * 16 + row16;
                float v = acc[i][j][r] + bcache[j];
                if (FINAL) {
                    Cf[(size_t)row * DMODEL + col] = v;
                } else {
                    if (mat <= 1) v = (v > 0.f) ? (v + 1.f) : __expf(v);  // elu+1
                    v *= mr;
                    Cb[(size_t)row * DMODEL + col] = f2bf(v);
                }
            }
        }
    }
}

// ---------- linear-attention scan (elementwise kv), chunked 3-pass ----------
#define SL    4096
#define SD    2048
#define SH    16
#define CHUNK 64
#define NCH   64   // SL / CHUNK

// Pass A: per-(b,h,chunk) partial sums.
__global__ void scan_partial_kernel(const unsigned short* __restrict__ k,
                                    const unsigned short* __restrict__ v,
                                    float* __restrict__ sumK, float* __restrict__ sumKV) {
    int blk = blockIdx.x;
    int c = blk & (NCH - 1), bh = blk >> 6;
    int b = bh >> 4, h = bh & (SH - 1);
    int lane = threadIdx.x;
    int tg = lane >> 4, dg = lane & 15;
    size_t base = ((size_t)(b * SL + c * CHUNK + tg)) * SD + h * 128 + dg * 8;
    float sk[8] = {0.f, 0.f, 0.f, 0.f, 0.f, 0.f, 0.f, 0.f};
    float skv[8] = {0.f, 0.f, 0.f, 0.f, 0.f, 0.f, 0.f, 0.f};
    for (int it = 0; it < CHUNK / 4; it++) {
        ushort8 kw = *(const ushort8*)(k + base);
        ushort8 vw = *(const ushort8*)(v + base);
        #pragma unroll
        for (int j = 0; j < 8; j++) {
            float kf = bf2f(kw[j]);
            float vf = bf2f(vw[j]);
            sk[j] += kf; skv[j] += kf * vf;
        }
        base += (size_t)4 * SD;
    }
    #pragma unroll
    for (int j = 0; j < 8; j++) {
        sk[j]  += __shfl_xor(sk[j], 16);  sk[j]  += __shfl_xor(sk[j], 32);
        skv[j] += __shfl_xor(skv[j], 16); skv[j] += __shfl_xor(skv[j], 32);
    }
    if (tg == 0) {
        size_t o = ((size_t)bh * NCH + c) * 128 + dg * 8;
        *(float4*)(sumK  + o)     = make_float4(sk[0], sk[1], sk[2], sk[3]);
        *(float4*)(sumK  + o + 4) = make_float4(sk[4], sk[5], sk[6], sk[7]);
        *(float4*)(sumKV + o)     = make_float4(skv[0], skv[1], skv[2], skv[3]);
        *(float4*)(sumKV + o + 4) = make_float4(skv[4], skv[5], skv[6], skv[7]);
    }
}

// Pass B: exclusive scan of chunk sums along chunk axis, per (b,h,d)
__global__ void scan_offsets_kernel(const float* __restrict__ sumK, const float* __restrict__ sumKV,
                                    float* __restrict__ offK, float* __restrict__ offKV) {
    int bh = blockIdx.x;
    int d  = threadIdx.x;   // 0..127
    float aK = 0.f, aKV = 0.f;
    for (int c = 0; c < NCH; c++) {
        size_t o = ((size_t)bh * NCH + c) * 128 + d;
        float sk = sumK[o], skv = sumKV[o];
        offK[o] = aK; offKV[o] = aKV;
        aK += sk; aKV += skv;
    }
}

// Pass C: within-chunk sequential scan, 4-timestep batches.
__global__ void scan_final_kernel(const unsigned short* __restrict__ q,
                                  const unsigned short* __restrict__ k,
                                  const unsigned short* __restrict__ v,
                                  const float* __restrict__ offK, const float* __restrict__ offKV,
                                  const float* __restrict__ mask,
                                  unsigned short* __restrict__ out) {
    int blk = blockIdx.x;
    int c = blk & (NCH - 1), bh = blk >> 6;
    int b = bh >> 4, h = bh & (SH - 1);
    int lane = threadIdx.x;
    size_t ob = ((size_t)bh * NCH + c) * 128 + 2 * lane;
    float2 kcv = *(const float2*)(offK  + ob);
    float2 kvv = *(const float2*)(offKV + ob);
    float kc0 = kcv.x, kc1 = kcv.y, kv0 = kvv.x, kv1 = kvv.y;
    size_t base = ((size_t)(b * SL + c * CHUNK)) * SD + h * 128 + 2 * lane;
    const float* mrow = mask + (size_t)b * SL + c * CHUNK;
    for (int s = 0; s < CHUNK / 4; s++) {
        unsigned kw[4], vw[4], qw[4];
        #pragma unroll
        for (int u = 0; u < 4; u++) {
            size_t a = base + (size_t)u * SD;
            kw[u] = *(const unsigned*)(k + a);
            vw[u] = *(const unsigned*)(v + a);
            qw[u] = *(const unsigned*)(q + a);
        }
        float p[4], n0[4], n1[4];
        #pragma unroll
        for (int u = 0; u < 4; u++) {
            float kk0 = bf2f(kw[u] & 0xffff), kk1 = bf2f(kw[u] >> 16);
            float vv0 = bf2f(vw[u] & 0xffff), vv1 = bf2f(vw[u] >> 16);
            float qq0 = bf2f(qw[u] & 0xffff), qq1 = bf2f(qw[u] >> 16);
            kc0 += kk0; kc1 += kk1;
            kv0 += kk0 * vv0; kv1 += kk1 * vv1;
            p[u]  = qq0 * kc0 + qq1 * kc1;
            n0[u] = qq0 * kv0; n1[u] = qq1 * kv1;
        }
        #pragma unroll
        for (int off = 32; off > 0; off >>= 1) {
            #pragma unroll
            for (int u = 0; u < 4; u++) p[u] += __shfl_xor(p[u], off);
        }
        #pragma unroll
        for (int u = 0; u < 4; u++) {
            float z = (p[u] + EPS_F) * mrow[s * 4 + u];
            float inv = 1.0f / z;
            unsigned o0 = f2bf(n0[u] * inv);
            unsigned o1 = f2bf(n1[u] * inv);
            *(unsigned*)(out + base + (size_t)u * SD) = o0 | (o1 << 16);
        }
        base += (size_t)4 * SD;
    }
}

// ---------- launcher ----------
extern "C" void kernel_launch(void* const* d_in, const int* in_sizes, int n_in,
                              void* d_out, int out_size, void* d_ws, size_t ws_size,
                              hipStream_t stream) {
    const float* x  = (const float*)d_in[0];
    const float* am = (const float*)d_in[1];
    const float* Wq = (const float*)d_in[2];
    const float* bq = (const float*)d_in[3];
    const float* Wk = (const float*)d_in[4];
    const float* bk = (const float*)d_in[5];
    const float* Wv = (const float*)d_in[6];
    const float* bv = (const float*)d_in[7];
    const float* Wo = (const float*)d_in[8];
    const float* bo = (const float*)d_in[9];
    float* out = (float*)d_out;

    const int Bb = 4, L = 4096, D = 2048;
    const int M = Bb * L;                       // 16384
    const size_t MD = (size_t)M * D;            // 33,554,432

    // workspace carve-up (~310 MB). attn aliases xb (xb dead after QKV GEMM).
    char* w = (char*)d_ws;
    unsigned short* xb    = (unsigned short*)w; w += MD * 2;
    unsigned short* qb    = (unsigned short*)w; w += MD * 2;
    unsigned short* kb    = (unsigned short*)w; w += MD * 2;
    unsigned short* vb    = (unsigned short*)w; w += MD * 2;
    unsigned short* WT    = (unsigned short*)w; w += (size_t)4 * D * D * 2; // [WqT;WkT;WvT;WoT]
    float* sumK  = (float*)w; w += (size_t)64 * NCH * 128 * 4;
    float* sumKV = (float*)w; w += (size_t)64 * NCH * 128 * 4;
    float* offK  = (float*)w; w += (size_t)64 * NCH * 128 * 4;
    float* offKV = (float*)w; w += (size_t)64 * NCH * 128 * 4;
    unsigned short* attnb = xb;                 // alias

    // 1) casts / transposes
    int n8 = (int)(MD / 8);
    cast_x_kernel<<<(n8 + 255) / 256, 256, 0, stream>>>(x, xb, n8);
    dim3 tb(32, 8);
    dim3 tg(D / 32, D / 32, 4);
    transpose_cast_kernel<<<tg, tb, 0, stream>>>(Wq, Wk, Wv, Wo, WT, D);

    // 2) fused QKV projection (N = 3*D), epilogues fused. grid 64x24 = 1536 (%8==0)
    dim3 gq(M / BMT, 3 * D / BNT);
    gemm_kernel<0><<<gq, 512, 0, stream>>>(xb, WT, bq, bk, bv, am, qb, kb, vb, nullptr, M, D);

    // 3) chunked linear-attention scan
    scan_partial_kernel<<<64 * NCH, 64, 0, stream>>>(kb, vb, sumK, sumKV);
    scan_offsets_kernel<<<64, 128, 0, stream>>>(sumK, sumKV, offK, offKV);
    scan_final_kernel<<<64 * NCH, 64, 0, stream>>>(qb, kb, vb, offK, offKV, am, attnb);

    // 4) output projection -> fp32 d_out. grid 64x8 = 512 (%8==0)
    dim3 go(M / BMT, D / BNT);
    gemm_kernel<1><<<go, 512, 0, stream>>>(attnb, WT + (size_t)3 * D * D, bo, nullptr, nullptr,
                                           nullptr, nullptr, nullptr, nullptr, out, M, D);
}